// Round 4
// baseline (335.272 us; speedup 1.0000x reference)
//
#include <hip/hip_runtime.h>
#include <hip/hip_bf16.h>

// Problem: B=8, T=4096, D=64, K=1024. N = B*T = 32768 rows.
// Inputs:  d_in[0] = x (f32, 2097152), d_in[1] = embeddings (f32, [D][K] = 64x1024)
// Output: FLOAT32, concatenated in return order:
//   quantized (2097152) | encodings (33554432) | indices (32768) | loss (1)

#define NROWS 32768
#define DDIM  64
#define KCB   1024
#define NSEG  8
#define SEG   128        // codes per K-segment

typedef float f32x4 __attribute__((ext_vector_type(4)));  // native vec for nontemporal stores

// ws layout (float index):
#define WS_ET    0        // Et [K][D] transposed embeddings (65536 f32)
#define WS_H     65536    // 0.5*||e_k||^2 (1024)
#define WS_LACC  66560    // f32 loss accumulator (1)
#define WS_CTR   66561    // u32 done-counter (1)
#define WS_PBEST 66564    // per-(seg,row) best score (8*32768 f32)
#define WS_PIDX  328708   // per-(seg,row) best index (8*32768 u16 = 131072 f32)
// end: 459780 f32 = 1.84 MB

// K1: transpose E (D,K) -> Et (K,D), h[k] = 0.5*||e_k||^2, zero loss acc + ctr.
__global__ __launch_bounds__(256) void k1_prep(const float* __restrict__ E,
                                               float* __restrict__ Et,
                                               float* __restrict__ h,
                                               float* __restrict__ lacc,
                                               unsigned int* __restrict__ ctr) {
  int k = blockIdx.x * 256 + threadIdx.x;   // 0..1023
  float col[DDIM];
  float sum = 0.f;
#pragma unroll
  for (int d = 0; d < DDIM; ++d) {
    float v = E[d * KCB + k];               // coalesced across lanes
    col[d] = v;
    sum = fmaf(v, v, sum);
  }
  float4* dst = (float4*)(Et + (size_t)k * DDIM);
#pragma unroll
  for (int i = 0; i < 16; ++i)
    dst[i] = make_float4(col[4*i], col[4*i+1], col[4*i+2], col[4*i+3]);
  h[k] = 0.5f * sum;
  if (k == 0) { lacc[0] = 0.f; ctr[0] = 0u; }
}

// K2: per (row, K-segment) partial argmax of score = x.e_k - 0.5||e_k||^2.
// x held in VGPRs (launch_bounds caps VGPRs at 128 -> no remat of xv);
// Et/h are wave-uniform -> scalar loads through SGPRs.
__global__ __launch_bounds__(256, 4) void k2_score(const float* __restrict__ x,
                                                   const float* __restrict__ Et,
                                                   const float* __restrict__ h,
                                                   float* __restrict__ pbest,
                                                   unsigned short* __restrict__ pidx) {
  int bid = blockIdx.x;            // 0..1023
  int ks  = bid >> 7;              // segment 0..7 (consecutive blocks share Et seg in L2)
  int n   = (bid & 127) * 256 + threadIdx.x;

  const float4* xr = (const float4*)(x + (size_t)n * DDIM);
  float4 xv[16];
#pragma unroll
  for (int i = 0; i < 16; ++i) xv[i] = xr[i];

  const float4* Ef4 = (const float4*)Et;
  int kbase = ks * SEG;
  float best = -3.0e38f;
  int besti = kbase;

  for (int k0 = kbase; k0 < kbase + SEG; k0 += 8) {
    float acc[8];
#pragma unroll
    for (int j = 0; j < 8; ++j) acc[j] = -h[k0 + j];
#pragma unroll
    for (int i = 0; i < 16; ++i) {
      float4 xi = xv[i];
#pragma unroll
      for (int j = 0; j < 8; ++j) {
        float4 e4 = Ef4[(k0 + j) * 16 + i];   // wave-uniform -> s_load
        acc[j] = fmaf(xi.x, e4.x, acc[j]);
        acc[j] = fmaf(xi.y, e4.y, acc[j]);
        acc[j] = fmaf(xi.z, e4.z, acc[j]);
        acc[j] = fmaf(xi.w, e4.w, acc[j]);
      }
    }
#pragma unroll
    for (int j = 0; j < 8; ++j) {
      if (acc[j] > best) { best = acc[j]; besti = k0 + j; }  // strict >: first max wins
    }
  }
  pbest[ks * NROWS + n] = best;
  pidx [ks * NROWS + n] = (unsigned short)besti;
}

// K3 fused: combine segments -> index; write indices, quantized, loss, one-hot
// encodings; last block finalizes loss. 2048 blocks x 16 rows.
__global__ __launch_bounds__(256) void k3_fused(const float* __restrict__ x,
                                                const float* __restrict__ Et,
                                                const float* __restrict__ pbest,
                                                const unsigned short* __restrict__ pidx,
                                                float* __restrict__ lacc,
                                                unsigned int* __restrict__ ctr,
                                                float* __restrict__ out_q,
                                                float* __restrict__ out_enc,
                                                float* __restrict__ out_ind,
                                                float* __restrict__ out_loss) {
  __shared__ int sidx[16];
  int tid = threadIdx.x;
  int r0 = blockIdx.x * 16;

  float lsum = 0.f;
  if (tid < 16) {
    int n = r0 + tid;
    float best = pbest[n];
    int bi = pidx[n];
#pragma unroll
    for (int q = 1; q < NSEG; ++q) {          // ascending segs: first-occurrence ties
      float b = pbest[q * NROWS + n];
      int i2 = (int)pidx[q * NROWS + n];
      if (b > best) { best = b; bi = i2; }
    }
    sidx[tid] = bi;
    out_ind[n] = (float)bi;

    const float4* xr = (const float4*)(x + (size_t)n * DDIM);
    const float4* qr = (const float4*)(Et + (size_t)bi * DDIM);
    float4* qw = (float4*)(out_q + (size_t)n * DDIM);
#pragma unroll
    for (int i = 0; i < 16; ++i) {
      float4 q4 = qr[i];
      float4 x4 = xr[i];
      float d0 = q4.x - x4.x, d1 = q4.y - x4.y, d2 = q4.z - x4.z, d3 = q4.w - x4.w;
      lsum = fmaf(d0, d0, lsum); lsum = fmaf(d1, d1, lsum);
      lsum = fmaf(d2, d2, lsum); lsum = fmaf(d3, d3, lsum);
      qw[i] = q4;
    }
  }
  // reduce lsum over wave 0 (only lanes 0..15 nonzero) and add to global acc
#pragma unroll
  for (int off = 8; off > 0; off >>= 1) lsum += __shfl_down(lsum, off);
  if (tid == 0) atomicAdd(lacc, lsum);
  __syncthreads();

  // one-hot encodings: thread t covers cols [4t, 4t+4) of each row
#pragma unroll
  for (int r = 0; r < 16; ++r) {
    int bk = sidx[r];                 // LDS broadcast
    f32x4 v = (f32x4)(0.f);
    if ((bk >> 2) == tid) {
      int j = bk & 3;
      v[j] = 1.0f;
    }
    __builtin_nontemporal_store(v, (f32x4*)(out_enc + (size_t)(r0 + r) * KCB + tid * 4));
  }

  // loss finalize: last block to arrive writes it
  if (tid == 0) {
    __threadfence();
    unsigned int old = atomicAdd(ctr, 1u);
    if (old == (unsigned int)(gridDim.x - 1)) {
      float total = atomicAdd(lacc, 0.0f);    // device-coherent read
      out_loss[0] = total * (1.0f / 2097152.0f);
    }
  }
}

extern "C" void kernel_launch(void* const* d_in, const int* in_sizes, int n_in,
                              void* d_out, int out_size, void* d_ws, size_t ws_size,
                              hipStream_t stream) {
  const float* x = (const float*)d_in[0];
  const float* E = (const float*)d_in[1];

  float* ws    = (float*)d_ws;
  float* Et    = ws + WS_ET;
  float* h     = ws + WS_H;
  float* lacc  = ws + WS_LACC;
  unsigned int* ctr = (unsigned int*)(ws + WS_CTR);
  float* pbest = ws + WS_PBEST;
  unsigned short* pidx = (unsigned short*)(ws + WS_PIDX);

  float* out      = (float*)d_out;
  float* out_q    = out;                      // 2097152
  float* out_enc  = out + 2097152;            // 33554432
  float* out_ind  = out + 35651584;           // 32768
  float* out_loss = out + 35684352;           // 1

  k1_prep<<<4, 256, 0, stream>>>(E, Et, h, lacc, ctr);
  k2_score<<<1024, 256, 0, stream>>>(x, Et, h, pbest, pidx);
  k3_fused<<<2048, 256, 0, stream>>>(x, Et, pbest, pidx, lacc, ctr,
                                     out_q, out_enc, out_ind, out_loss);
}

// Round 5
// 258.155 us; speedup vs baseline: 1.2987x; 1.2987x over previous
//
#include <hip/hip_runtime.h>
#include <hip/hip_bf16.h>

// Problem: B=8, T=4096, D=64, K=1024. N = B*T = 32768 rows.
// Inputs:  d_in[0] = x (f32, 2097152), d_in[1] = embeddings (f32, [D][K] = 64x1024)
// Output: FLOAT32, concatenated in return order:
//   quantized (2097152) | encodings (33554432) | indices (32768) | loss (1)

#define NROWS 32768
#define DDIM  64
#define KCB   1024
#define NSEG  8
#define SEG   128        // codes per K-segment

typedef float f32x4 __attribute__((ext_vector_type(4)));

// ws layout (float index):
#define WS_ET    0        // Et [K][D] transposed embeddings (65536 f32)
#define WS_H     65536    // 0.5*||e_k||^2 (1024)
#define WS_PART  66560    // per-block loss partials (128 f32)
#define WS_IBEST 66688    // final index per row (32768 int)
#define WS_PBEST 99456    // per-(seg,row) best score (8*32768 f32)
#define WS_PIDX  361600   // per-(seg,row) best index (8*32768 u16 = 131072 f32)
// end: 492672 f32 = 1.97 MB

// K1: transpose E (D,K) -> Et (K,D), h[k] = 0.5*||e_k||^2.
__global__ __launch_bounds__(256) void k1_prep(const float* __restrict__ E,
                                               float* __restrict__ Et,
                                               float* __restrict__ h) {
  int k = blockIdx.x * 256 + threadIdx.x;   // 0..1023
  float col[DDIM];
  float sum = 0.f;
#pragma unroll
  for (int d = 0; d < DDIM; ++d) {
    float v = E[d * KCB + k];               // coalesced across lanes
    col[d] = v;
    sum = fmaf(v, v, sum);
  }
  float4* dst = (float4*)(Et + (size_t)k * DDIM);
#pragma unroll
  for (int i = 0; i < 16; ++i)
    dst[i] = make_float4(col[4*i], col[4*i+1], col[4*i+2], col[4*i+3]);
  h[k] = 0.5f * sum;
}

// K2: per (row, K-segment) partial argmax of score = x.e_k - 0.5||e_k||^2.
// x held in VGPRs (launch_bounds caps VGPRs at 128); Et/h wave-uniform -> s_loads.
__global__ __launch_bounds__(256, 4) void k2_score(const float* __restrict__ x,
                                                   const float* __restrict__ Et,
                                                   const float* __restrict__ h,
                                                   float* __restrict__ pbest,
                                                   unsigned short* __restrict__ pidx) {
  int bid = blockIdx.x;            // 0..1023
  int ks  = bid >> 7;              // segment 0..7 (consecutive blocks share Et seg in L2)
  int n   = (bid & 127) * 256 + threadIdx.x;

  const float4* xr = (const float4*)(x + (size_t)n * DDIM);
  float4 xv[16];
#pragma unroll
  for (int i = 0; i < 16; ++i) xv[i] = xr[i];

  const float4* Ef4 = (const float4*)Et;
  int kbase = ks * SEG;
  float best = -3.0e38f;
  int besti = kbase;

  for (int k0 = kbase; k0 < kbase + SEG; k0 += 8) {
    float acc[8];
#pragma unroll
    for (int j = 0; j < 8; ++j) acc[j] = -h[k0 + j];
#pragma unroll
    for (int i = 0; i < 16; ++i) {
      float4 xi = xv[i];
#pragma unroll
      for (int j = 0; j < 8; ++j) {
        float4 e4 = Ef4[(k0 + j) * 16 + i];   // wave-uniform -> s_load
        acc[j] = fmaf(xi.x, e4.x, acc[j]);
        acc[j] = fmaf(xi.y, e4.y, acc[j]);
        acc[j] = fmaf(xi.z, e4.z, acc[j]);
        acc[j] = fmaf(xi.w, e4.w, acc[j]);
      }
    }
#pragma unroll
    for (int j = 0; j < 8; ++j) {
      if (acc[j] > best) { best = acc[j]; besti = k0 + j; }  // strict >: first max wins
    }
  }
  pbest[ks * NROWS + n] = best;
  pidx [ks * NROWS + n] = (unsigned short)besti;
}

// K3: one thread per row. Combine segments -> index; write indices + quantized;
// block-reduced loss partial (NO global atomics).
__global__ __launch_bounds__(256) void k3_rows(const float* __restrict__ x,
                                               const float* __restrict__ Et,
                                               const float* __restrict__ pbest,
                                               const unsigned short* __restrict__ pidx,
                                               int* __restrict__ ibest,
                                               float* __restrict__ partial,
                                               float* __restrict__ out_q,
                                               float* __restrict__ out_ind) {
  int n = blockIdx.x * 256 + threadIdx.x;
  float best = pbest[n];
  int bi = pidx[n];
#pragma unroll
  for (int q = 1; q < NSEG; ++q) {            // ascending segs: first-occurrence ties
    float b = pbest[q * NROWS + n];
    int i2 = (int)pidx[q * NROWS + n];
    if (b > best) { best = b; bi = i2; }
  }
  ibest[n] = bi;
  out_ind[n] = (float)bi;

  const float4* xr = (const float4*)(x + (size_t)n * DDIM);
  const float4* qr = (const float4*)(Et + (size_t)bi * DDIM);
  float4* qw = (float4*)(out_q + (size_t)n * DDIM);
  float lsum = 0.f;
#pragma unroll
  for (int i = 0; i < 16; ++i) {
    float4 q4 = qr[i];
    float4 x4 = xr[i];
    float d0 = q4.x - x4.x, d1 = q4.y - x4.y, d2 = q4.z - x4.z, d3 = q4.w - x4.w;
    lsum = fmaf(d0, d0, lsum); lsum = fmaf(d1, d1, lsum);
    lsum = fmaf(d2, d2, lsum); lsum = fmaf(d3, d3, lsum);
    qw[i] = q4;
  }

  // block loss reduction: wave shfl -> LDS -> single plain store per block
#pragma unroll
  for (int off = 32; off > 0; off >>= 1) lsum += __shfl_down(lsum, off);
  __shared__ float red[4];
  int lane = threadIdx.x & 63, w = threadIdx.x >> 6;
  if (lane == 0) red[w] = lsum;
  __syncthreads();
  if (threadIdx.x == 0) partial[blockIdx.x] = red[0] + red[1] + red[2] + red[3];
}

// K4: streaming one-hot encodings writer. Thread t covers cols [4t,4t+4).
// No atomics, no fences — pure write stream.
__global__ __launch_bounds__(256) void k4_enc(const int* __restrict__ ibest,
                                              float* __restrict__ out_enc) {
  int t = threadIdx.x;
  int r0 = blockIdx.x * 16;
#pragma unroll
  for (int r = 0; r < 16; ++r) {
    int row = r0 + r;
    int bk = ibest[row];              // wave-uniform broadcast load
    f32x4 v = (f32x4)(0.f);
    if ((bk >> 2) == t) v[bk & 3] = 1.0f;
    __builtin_nontemporal_store(v, (f32x4*)(out_enc + (size_t)row * KCB + t * 4));
  }
}

// K5: reduce 128 partials -> loss.
__global__ void k5_loss(const float* __restrict__ partial, float* __restrict__ out_loss) {
  int t = threadIdx.x;                 // 64 threads
  float s = partial[t] + partial[t + 64];
#pragma unroll
  for (int off = 32; off > 0; off >>= 1) s += __shfl_down(s, off);
  if (t == 0) out_loss[0] = s * (1.0f / 2097152.0f);
}

extern "C" void kernel_launch(void* const* d_in, const int* in_sizes, int n_in,
                              void* d_out, int out_size, void* d_ws, size_t ws_size,
                              hipStream_t stream) {
  const float* x = (const float*)d_in[0];
  const float* E = (const float*)d_in[1];

  float* ws    = (float*)d_ws;
  float* Et    = ws + WS_ET;
  float* h     = ws + WS_H;
  float* part  = ws + WS_PART;
  int*   ibest = (int*)(ws + WS_IBEST);
  float* pbest = ws + WS_PBEST;
  unsigned short* pidx = (unsigned short*)(ws + WS_PIDX);

  float* out      = (float*)d_out;
  float* out_q    = out;                      // 2097152
  float* out_enc  = out + 2097152;            // 33554432
  float* out_ind  = out + 35651584;           // 32768
  float* out_loss = out + 35684352;           // 1

  k1_prep<<<4, 256, 0, stream>>>(E, Et, h);
  k2_score<<<1024, 256, 0, stream>>>(x, Et, h, pbest, pidx);
  k3_rows<<<128, 256, 0, stream>>>(x, Et, pbest, pidx, ibest, part, out_q, out_ind);
  k4_enc<<<2048, 256, 0, stream>>>(ibest, out_enc);
  k5_loss<<<1, 64, 0, stream>>>(part, out_loss);
}

// Round 6
// 246.370 us; speedup vs baseline: 1.3608x; 1.0478x over previous
//
#include <hip/hip_runtime.h>
#include <hip/hip_bf16.h>

// Problem: B=8, T=4096, D=64, K=1024. N = B*T = 32768 rows.
// Inputs:  d_in[0] = x (f32, 2097152), d_in[1] = embeddings (f32, [D][K] = 64x1024)
// Output: FLOAT32, concatenated in return order:
//   quantized (2097152) | encodings (33554432) | indices (32768) | loss (1)

#define NROWS 32768
#define DDIM  64
#define KCB   1024
#define NSEG  8
#define SEG   128        // codes per K-segment

typedef float f32x4 __attribute__((ext_vector_type(4)));

// ws layout (float index):
#define WS_ET    0        // Et [K][D] transposed embeddings (65536 f32)
#define WS_H     65536    // 0.5*||e_k||^2 (1024)
#define WS_PART  66560    // per-block loss partials (128 f32)
#define WS_IBEST 66688    // final index per row (32768 int)
#define WS_PBEST 99456    // per-(seg,row) best score (8*32768 f32)
#define WS_PIDX  361600   // per-(seg,row) best index (8*32768 u16 = 131072 f32)
// end: 492672 f32 = 1.97 MB

// K1: transpose E (D,K) -> Et (K,D), h[k] = 0.5*||e_k||^2.
__global__ __launch_bounds__(256) void k1_prep(const float* __restrict__ E,
                                               float* __restrict__ Et,
                                               float* __restrict__ h) {
  int k = blockIdx.x * 256 + threadIdx.x;   // 0..1023
  float col[DDIM];
  float sum = 0.f;
#pragma unroll
  for (int d = 0; d < DDIM; ++d) {
    float v = E[d * KCB + k];               // coalesced across lanes
    col[d] = v;
    sum = fmaf(v, v, sum);
  }
  float4* dst = (float4*)(Et + (size_t)k * DDIM);
#pragma unroll
  for (int i = 0; i < 16; ++i)
    dst[i] = make_float4(col[4*i], col[4*i+1], col[4*i+2], col[4*i+3]);
  h[k] = 0.5f * sum;
}

// K2: per (row, K-segment) partial argmax of score = x.e_k - 0.5||e_k||^2.
// E-segment staged in LDS (32KB): uniform ds_read broadcast, no SGPR pressure.
// x row held in 64 VGPRs; asm memory clobber + barrier forbid re-load sinking.
__global__ __launch_bounds__(256, 3) void k2_score(const float* __restrict__ x,
                                                   const float* __restrict__ Et,
                                                   const float* __restrict__ h,
                                                   float* __restrict__ pbest,
                                                   unsigned short* __restrict__ pidx) {
  __shared__ float se[SEG * DDIM];   // 32 KB E-tile [k][d]
  __shared__ float sh[SEG];          // 0.5*||e||^2 for the segment

  int bid = blockIdx.x;              // 0..1023
  int ks  = bid >> 7;                // segment 0..7 (128 consecutive blocks share seg)
  int tid = threadIdx.x;
  int n   = (bid & 127) * 256 + tid;

  // cooperative stage: 2048 float4, 8 per thread, fully coalesced
  {
    const float4* src = (const float4*)(Et + (size_t)ks * SEG * DDIM);
    float4* dst = (float4*)se;
#pragma unroll
    for (int i = 0; i < 8; ++i) {
      int f = tid + i * 256;
      dst[f] = src[f];
    }
    if (tid < SEG) sh[tid] = h[ks * SEG + tid];
  }

  // x row -> registers (must stay resident: loads may not sink past the clobber)
  const float4* xr = (const float4*)(x + (size_t)n * DDIM);
  float4 xv[16];
#pragma unroll
  for (int i = 0; i < 16; ++i) xv[i] = xr[i];
  asm volatile("" ::: "memory");
  __syncthreads();

  float best = -3.0e38f;
  int besti = ks * SEG;

#pragma unroll 1
  for (int kg = 0; kg < SEG; kg += 8) {
    float acc[8];
#pragma unroll
    for (int j = 0; j < 8; ++j) acc[j] = -sh[kg + j];
#pragma unroll
    for (int i = 0; i < 16; ++i) {
      float4 xi = xv[i];
#pragma unroll
      for (int j = 0; j < 8; ++j) {
        float4 e4 = *(const float4*)(se + (kg + j) * DDIM + i * 4);  // uniform -> broadcast
        acc[j] = fmaf(xi.x, e4.x, acc[j]);
        acc[j] = fmaf(xi.y, e4.y, acc[j]);
        acc[j] = fmaf(xi.z, e4.z, acc[j]);
        acc[j] = fmaf(xi.w, e4.w, acc[j]);
      }
    }
#pragma unroll
    for (int j = 0; j < 8; ++j) {
      if (acc[j] > best) { best = acc[j]; besti = ks * SEG + kg + j; }  // strict >: first wins
    }
  }
  pbest[ks * NROWS + n] = best;
  pidx [ks * NROWS + n] = (unsigned short)besti;
}

// K3: one thread per row. Combine segments -> index; write indices + quantized;
// block-reduced loss partial (no global atomics).
__global__ __launch_bounds__(256) void k3_rows(const float* __restrict__ x,
                                               const float* __restrict__ Et,
                                               const float* __restrict__ pbest,
                                               const unsigned short* __restrict__ pidx,
                                               int* __restrict__ ibest,
                                               float* __restrict__ partial,
                                               float* __restrict__ out_q,
                                               float* __restrict__ out_ind) {
  int n = blockIdx.x * 256 + threadIdx.x;
  float best = pbest[n];
  int bi = pidx[n];
#pragma unroll
  for (int q = 1; q < NSEG; ++q) {            // ascending segs: first-occurrence ties
    float b = pbest[q * NROWS + n];
    int i2 = (int)pidx[q * NROWS + n];
    if (b > best) { best = b; bi = i2; }
  }
  ibest[n] = bi;
  out_ind[n] = (float)bi;

  const float4* xr = (const float4*)(x + (size_t)n * DDIM);
  const float4* qr = (const float4*)(Et + (size_t)bi * DDIM);
  float4* qw = (float4*)(out_q + (size_t)n * DDIM);
  float lsum = 0.f;
#pragma unroll
  for (int i = 0; i < 16; ++i) {
    float4 q4 = qr[i];
    float4 x4 = xr[i];
    float d0 = q4.x - x4.x, d1 = q4.y - x4.y, d2 = q4.z - x4.z, d3 = q4.w - x4.w;
    lsum = fmaf(d0, d0, lsum); lsum = fmaf(d1, d1, lsum);
    lsum = fmaf(d2, d2, lsum); lsum = fmaf(d3, d3, lsum);
    qw[i] = q4;
  }

#pragma unroll
  for (int off = 32; off > 0; off >>= 1) lsum += __shfl_down(lsum, off);
  __shared__ float red[4];
  int lane = threadIdx.x & 63, w = threadIdx.x >> 6;
  if (lane == 0) red[w] = lsum;
  __syncthreads();
  if (threadIdx.x == 0) partial[blockIdx.x] = red[0] + red[1] + red[2] + red[3];
}

// K4: streaming one-hot encodings writer. ibest[16] prefetched as one s_load batch.
__global__ __launch_bounds__(256) void k4_enc(const int* __restrict__ ibest,
                                              float* __restrict__ out_enc) {
  int t = threadIdx.x;
  int r0 = blockIdx.x * 16;
  int idx[16];
#pragma unroll
  for (int r = 0; r < 16; ++r) idx[r] = ibest[r0 + r];   // uniform -> batched s_loads
#pragma unroll
  for (int r = 0; r < 16; ++r) {
    f32x4 v = (f32x4)(0.f);
    if ((idx[r] >> 2) == t) v[idx[r] & 3] = 1.0f;
    __builtin_nontemporal_store(v, (f32x4*)(out_enc + (size_t)(r0 + r) * KCB + t * 4));
  }
}

// K5: reduce 128 partials -> loss.
__global__ void k5_loss(const float* __restrict__ partial, float* __restrict__ out_loss) {
  int t = threadIdx.x;                 // 64 threads
  float s = partial[t] + partial[t + 64];
#pragma unroll
  for (int off = 32; off > 0; off >>= 1) s += __shfl_down(s, off);
  if (t == 0) out_loss[0] = s * (1.0f / 2097152.0f);
}

extern "C" void kernel_launch(void* const* d_in, const int* in_sizes, int n_in,
                              void* d_out, int out_size, void* d_ws, size_t ws_size,
                              hipStream_t stream) {
  const float* x = (const float*)d_in[0];
  const float* E = (const float*)d_in[1];

  float* ws    = (float*)d_ws;
  float* Et    = ws + WS_ET;
  float* h     = ws + WS_H;
  float* part  = ws + WS_PART;
  int*   ibest = (int*)(ws + WS_IBEST);
  float* pbest = ws + WS_PBEST;
  unsigned short* pidx = (unsigned short*)(ws + WS_PIDX);

  float* out      = (float*)d_out;
  float* out_q    = out;                      // 2097152
  float* out_enc  = out + 2097152;            // 33554432
  float* out_ind  = out + 35651584;           // 32768
  float* out_loss = out + 35684352;           // 1

  k1_prep<<<4, 256, 0, stream>>>(E, Et, h);
  k2_score<<<1024, 256, 0, stream>>>(x, Et, h, pbest, pidx);
  k3_rows<<<128, 256, 0, stream>>>(x, Et, pbest, pidx, ibest, part, out_q, out_ind);
  k4_enc<<<2048, 256, 0, stream>>>(ibest, out_enc);
  k5_loss<<<1, 64, 0, stream>>>(part, out_loss);
}